// Round 3
// baseline (6591.906 us; speedup 1.0000x reference)
//
#include <hip/hip_runtime.h>
#include <hip/hip_bf16.h>
#include <stdint.h>

// ---------------------------------------------------------------------------
// BiLSTM (H=256, fwd+rev) -> sentence LSTM (512->512) -> linear -> CRF(16)
// Round 3: fine-grained producer/consumer recurrences.
//   - sync groups = blocks sharing batch rows only (4 for fr, 16 for s)
//   - h exchange via agent-scope atomic 8B ops (L3-coherent, NO threadfence,
//     NO L2 invalidation -> gx/gs stay L2-warm)
//   - per-block flag incremented once per wave with RELEASE (waitcnt drains
//     that wave's h stores); consumers ACQUIRE-poll flags (one gathered load)
//   - MFMA A=W rows, B=h rows -> D row = hid, col = batch: all 4 gates of a
//     (batch,hid) land in ONE lane -> in-lane epilogue, 8B packed h store
// ---------------------------------------------------------------------------

typedef __bf16 bf16_t;
typedef __bf16 bf16x8 __attribute__((ext_vector_type(8)));
typedef __bf16 bf16x4v __attribute__((ext_vector_type(4)));
typedef float f32x4 __attribute__((ext_vector_type(4)));

#define MFMA_BF16(a, b, c) __builtin_amdgcn_mfma_f32_16x16x32_bf16((a), (b), (c), 0, 0, 0)

__device__ __forceinline__ float sigm_(float x) { return 1.f / (1.f + __expf(-x)); }
__device__ __forceinline__ float tanh_(float x) {
  x = fminf(20.f, fmaxf(-20.f, x));
  float e = __expf(-2.f * x);
  return (1.f - e) / (1.f + e);
}

__device__ __forceinline__ unsigned long long aload8(const unsigned long long* p) {
  return __hip_atomic_load(p, __ATOMIC_RELAXED, __HIP_MEMORY_SCOPE_AGENT);
}
__device__ __forceinline__ void astore8(unsigned long long* p, unsigned long long v) {
  __hip_atomic_store(p, v, __ATOMIC_RELAXED, __HIP_MEMORY_SCOPE_AGENT);
}

union U16 { struct { unsigned long long a, b; } s; bf16x8 v; };
union U8  { bf16x4v v; unsigned long long u; };

__global__ void init_bar(unsigned* flags) {
  int i = blockIdx.x * 256 + threadIdx.x;
  if (i < 4096) flags[i] = 0u;
}

// ---------------------------- fp32 -> bf16 convert -------------------------
__global__ void cvt4(const float* __restrict__ in, bf16_t* __restrict__ out, int n4) {
  int i = blockIdx.x * blockDim.x + threadIdx.x;
  int stride = gridDim.x * blockDim.x;
  for (; i < n4; i += stride) {
    float4 v = ((const float4*)in)[i];
    bf16x4v o;
    o.x = (bf16_t)v.x; o.y = (bf16_t)v.y; o.z = (bf16_t)v.z; o.w = (bf16_t)v.w;
    ((bf16x4v*)out)[i] = o;
  }
}

// ------------------------------- bf16 GEMM ---------------------------------
__global__ void __launch_bounds__(256, 2)
gemm_bt(const bf16_t* __restrict__ A, const bf16_t* __restrict__ B,
        bf16_t* __restrict__ C, int M, int N, int K) {
  const int tid = threadIdx.x;
  const int w = tid >> 6, lane = tid & 63, quad = lane >> 4, l15 = lane & 15;
  const int ntiles = N >> 7;
  const int m0 = (blockIdx.x / ntiles) << 7;
  const int n0 = (blockIdx.x % ntiles) << 7;
  const int wm = (w >> 1) << 6, wn = (w & 1) << 6;

  __shared__ bf16_t As[128 * 72];
  __shared__ bf16_t Bs[128 * 72];

  const f32x4 z4 = {0.f, 0.f, 0.f, 0.f};
  f32x4 acc[4][4];
#pragma unroll
  for (int i = 0; i < 4; ++i)
#pragma unroll
    for (int j = 0; j < 4; ++j) acc[i][j] = z4;

  const int nk = K >> 6;
  for (int kt = 0; kt < nk; ++kt) {
    uint4 av[4], bv[4];
#pragma unroll
    for (int i = 0; i < 4; ++i) {
      int cid = tid + i * 256;
      int r = cid >> 3, c = cid & 7;
      av[i] = *(const uint4*)&A[(size_t)(m0 + r) * K + kt * 64 + c * 8];
      bv[i] = *(const uint4*)&B[(size_t)(n0 + r) * K + kt * 64 + c * 8];
    }
    __syncthreads();
#pragma unroll
    for (int i = 0; i < 4; ++i) {
      int cid = tid + i * 256;
      int r = cid >> 3, c = cid & 7;
      *(uint4*)&As[r * 72 + c * 8] = av[i];
      *(uint4*)&Bs[r * 72 + c * 8] = bv[i];
    }
    __syncthreads();
#pragma unroll
    for (int s = 0; s < 2; ++s) {
      bf16x8 af[4], bfr[4];
#pragma unroll
      for (int i = 0; i < 4; ++i)
        af[i] = *(const bf16x8*)&As[(wm + i * 16 + l15) * 72 + s * 32 + quad * 8];
#pragma unroll
      for (int j = 0; j < 4; ++j)
        bfr[j] = *(const bf16x8*)&Bs[(wn + j * 16 + l15) * 72 + s * 32 + quad * 8];
#pragma unroll
      for (int i = 0; i < 4; ++i)
#pragma unroll
        for (int j = 0; j < 4; ++j)
          acc[i][j] = MFMA_BF16(af[i], bfr[j], acc[i][j]);
    }
  }
#pragma unroll
  for (int i = 0; i < 4; ++i)
#pragma unroll
    for (int j = 0; j < 4; ++j)
#pragma unroll
      for (int p = 0; p < 4; ++p) {
        int row = m0 + wm + i * 16 + quad * 4 + p;
        int col = n0 + wn + j * 16 + l15;
        C[(size_t)row * N + col] = (bf16_t)acc[i][j][p];
      }
}

// ----------------------- fwd/rev LSTM recurrence ---------------------------
// 128 blocks = dir(2) x bg(16: 16 rows) x hsp(4: 64 hid). Sync group = 4.
// hb layout: [par(2)][dir(2)][256 rows][256 hid] bf16.
__global__ void __launch_bounds__(256, 1)
lstm_fr(const bf16_t* __restrict__ gx, const bf16_t* __restrict__ whh,
        const float* __restrict__ b_f, const float* __restrict__ b_r,
        bf16_t* __restrict__ h_cat, bf16_t* __restrict__ hb,
        unsigned* __restrict__ flags) {
  const int tid = threadIdx.x;
  const int w = tid >> 6, lane = tid & 63, quad = lane >> 4, l15 = lane & 15;
  const int dir = blockIdx.x >> 6;
  const int bg = (blockIdx.x >> 2) & 15;
  const int hsp = blockIdx.x & 3;
  const int rows0 = bg << 4;
  const int hid0 = hsp << 6;
  unsigned* fbase = flags + (dir * 16 + bg) * 4 * 16;   // 4 flags, 64B apart
  unsigned* fmine = fbase + hsp * 16;

  __shared__ bf16_t Ws[256 * 264];   // packed row = g*64+hh, K=256 (+8 pad)
  const bf16_t* Wg = whh + (size_t)dir * 262144;
#pragma unroll
  for (int i = 0; i < 32; ++i) {
    int id = tid + i * 256;          // 8192 = 256 rows x 32 chunks(16B)
    int r = id >> 5, c = id & 31;
    int g = r >> 6, hh = r & 63;
    *(uint4*)&Ws[r * 264 + c * 8] =
        *(const uint4*)&Wg[(size_t)(g * 256 + hid0 + hh) * 256 + c * 8];
  }
  const float* bias = dir ? b_r : b_f;
  const int hid = hid0 + w * 16 + quad * 4;   // 4 consecutive hid per lane
  float br[4][4];
#pragma unroll
  for (int g = 0; g < 4; ++g)
#pragma unroll
    for (int p = 0; p < 4; ++p) br[g][p] = bias[g * 256 + hid + p];
  const int brow = rows0 + l15;
  float c4[4] = {0.f, 0.f, 0.f, 0.f};
  const f32x4 z4 = {0.f, 0.f, 0.f, 0.f};
  __syncthreads();

  for (int t = 1; t <= 128; ++t) {
    const int tt = dir ? (128 - t) : (t - 1);
    // gate prefetch: independent of flags, overlaps the poll
    const size_t gbase = ((size_t)brow * 128 + tt) * 2048 + (size_t)dir * 1024;
    bf16x4v gp[4];
#pragma unroll
    for (int g = 0; g < 4; ++g) gp[g] = *(const bf16x4v*)&gx[gbase + g * 256 + hid];

    f32x4 acc[4];
#pragma unroll
    for (int g = 0; g < 4; ++g) acc[g] = z4;

    if (t >= 2) {
      const unsigned tgt = 4u * (unsigned)(t - 1);
      const unsigned* fp = fbase + (lane & 3) * 16;
      for (;;) {
        unsigned f = __hip_atomic_load(fp, __ATOMIC_ACQUIRE, __HIP_MEMORY_SCOPE_AGENT);
        if (__all((int)(f >= tgt))) break;
        __builtin_amdgcn_s_sleep(1);
      }
      const unsigned long long* hrow = (const unsigned long long*)
          (hb + (((size_t)((t & 1) ^ 1) * 2 + dir) * 256 + brow) * 256);
#pragma unroll
      for (int ks = 0; ks < 8; ++ks) {
        U16 u;
        u.s.a = aload8(hrow + ks * 8 + quad * 2);
        u.s.b = aload8(hrow + ks * 8 + quad * 2 + 1);
#pragma unroll
        for (int g = 0; g < 4; ++g) {
          bf16x8 af = *(const bf16x8*)&Ws[(g * 64 + w * 16 + l15) * 264 + ks * 32 + quad * 8];
          acc[g] = MFMA_BF16(af, u.v, acc[g]);
        }
      }
    }
    // epilogue: lane holds all 4 gates for (batch=brow, hid..hid+3)
    bf16x4v hv;
#pragma unroll
    for (int p = 0; p < 4; ++p) {
      float Pi = acc[0][p] + (float)gp[0][p] + br[0][p];
      float Pf = acc[1][p] + (float)gp[1][p] + br[1][p];
      float Pg = acc[2][p] + (float)gp[2][p] + br[2][p];
      float Po = acc[3][p] + (float)gp[3][p] + br[3][p];
      float cc = sigm_(Pf) * c4[p] + sigm_(Pi) * tanh_(Pg);
      c4[p] = cc;
      hv[p] = (bf16_t)(sigm_(Po) * tanh_(cc));
    }
    *(bf16x4v*)&h_cat[((size_t)brow * 128 + tt) * 512 + dir * 256 + hid] = hv;
    if (t < 128) {
      U8 cv; cv.v = hv;
      astore8((unsigned long long*)(hb + (((size_t)(t & 1) * 2 + dir) * 256 + brow) * 256 + hid),
              cv.u);
      if (lane == 0)
        __hip_atomic_fetch_add(fmine, 1u, __ATOMIC_RELEASE, __HIP_MEMORY_SCOPE_AGENT);
    }
  }
}

// ------------------------ sentence LSTM recurrence -------------------------
// 128 blocks = bg(8: 32 rows) x hsp(16: 32 hid). Sync group = 16.
// hb layout: [par(2)][256 rows][512 hid] bf16.
__global__ void __launch_bounds__(256, 1)
lstm_s(const bf16_t* __restrict__ gs, const bf16_t* __restrict__ wsh,
       const float* __restrict__ b_s, float* __restrict__ hT,
       bf16_t* __restrict__ hb, unsigned* __restrict__ flags) {
  const int tid = threadIdx.x;
  const int w = tid >> 6, lane = tid & 63, quad = lane >> 4, l15 = lane & 15;
  const int bg = blockIdx.x >> 4;
  const int hsp = blockIdx.x & 15;
  const int rows0 = bg << 5;
  const int hid0 = hsp << 5;
  const int nt = w & 1, hb2 = w >> 1;         // wave: batch-half, hid-half
  unsigned* fbase = flags + bg * 16 * 16;     // 16 flags, 64B apart
  unsigned* fmine = fbase + hsp * 16;

  __shared__ bf16_t Ws[128 * 520];   // packed row = g*32+hh, K=512 (+8 pad)
#pragma unroll
  for (int i = 0; i < 32; ++i) {
    int id = tid + i * 256;          // 8192 = 128 rows x 64 chunks(16B)
    int r = id >> 6, c = id & 63;
    int g = r >> 5, hh = r & 31;
    *(uint4*)&Ws[r * 520 + c * 8] =
        *(const uint4*)&wsh[(size_t)(g * 512 + hid0 + hh) * 512 + c * 8];
  }
  const int hid = hid0 + hb2 * 16 + quad * 4;
  float br[4][4];
#pragma unroll
  for (int g = 0; g < 4; ++g)
#pragma unroll
    for (int p = 0; p < 4; ++p) br[g][p] = b_s[g * 512 + hid + p];
  const int brow = rows0 + nt * 16 + l15;
  float c4[4] = {0.f, 0.f, 0.f, 0.f};
  const f32x4 z4 = {0.f, 0.f, 0.f, 0.f};
  __syncthreads();

  for (int t = 1; t <= 128; ++t) {
    const size_t gbase = ((size_t)brow * 128 + (t - 1)) * 2048;
    bf16x4v gp[4];
#pragma unroll
    for (int g = 0; g < 4; ++g) gp[g] = *(const bf16x4v*)&gs[gbase + g * 512 + hid];

    f32x4 acc[4];
#pragma unroll
    for (int g = 0; g < 4; ++g) acc[g] = z4;

    if (t >= 2) {
      const unsigned tgt = 4u * (unsigned)(t - 1);
      const unsigned* fp = fbase + (lane & 15) * 16;
      for (;;) {
        unsigned f = __hip_atomic_load(fp, __ATOMIC_ACQUIRE, __HIP_MEMORY_SCOPE_AGENT);
        if (__all((int)(f >= tgt))) break;
        __builtin_amdgcn_s_sleep(1);
      }
      const unsigned long long* hrow = (const unsigned long long*)
          (hb + ((size_t)((t & 1) ^ 1) * 256 + brow) * 512);
#pragma unroll
      for (int ks = 0; ks < 16; ++ks) {
        U16 u;
        u.s.a = aload8(hrow + ks * 8 + quad * 2);
        u.s.b = aload8(hrow + ks * 8 + quad * 2 + 1);
#pragma unroll
        for (int g = 0; g < 4; ++g) {
          bf16x8 af = *(const bf16x8*)&Ws[(g * 32 + hb2 * 16 + l15) * 520 + ks * 32 + quad * 8];
          acc[g] = MFMA_BF16(af, u.v, acc[g]);
        }
      }
    }
    bf16x4v hv;
    float hf[4];
#pragma unroll
    for (int p = 0; p < 4; ++p) {
      float Pi = acc[0][p] + (float)gp[0][p] + br[0][p];
      float Pf = acc[1][p] + (float)gp[1][p] + br[1][p];
      float Pg = acc[2][p] + (float)gp[2][p] + br[2][p];
      float Po = acc[3][p] + (float)gp[3][p] + br[3][p];
      float cc = sigm_(Pf) * c4[p] + sigm_(Pi) * tanh_(Pg);
      c4[p] = cc;
      hf[p] = sigm_(Po) * tanh_(cc);
      hv[p] = (bf16_t)hf[p];
    }
    if (t < 128) {
      U8 cv; cv.v = hv;
      astore8((unsigned long long*)(hb + ((size_t)(t & 1) * 256 + brow) * 512 + hid), cv.u);
      if (lane == 0)
        __hip_atomic_fetch_add(fmine, 1u, __ATOMIC_RELEASE, __HIP_MEMORY_SCOPE_AGENT);
    } else {
      *(float4*)&hT[(size_t)brow * 512 + hid] = make_float4(hf[0], hf[1], hf[2], hf[3]);
    }
  }
}

// ------------------------------- emissions ---------------------------------
__global__ void emis_k(const float* __restrict__ hT, const float* __restrict__ lin_w,
                       const float* __restrict__ lin_b, float* __restrict__ em) {
  const int idx = blockIdx.x * 256 + threadIdx.x;
  const int s = idx >> 4, c = idx & 15;
  const float4* h4 = (const float4*)(hT + (size_t)s * 512);
  const float4* w4 = (const float4*)(lin_w + (size_t)c * 512);
  float acc = lin_b[c];
  for (int k = 0; k < 128; ++k) {
    float4 a = h4[k], b = w4[k];
    acc += a.x * b.x + a.y * b.y + a.z * b.z + a.w * b.w;
  }
  em[idx] = acc;
}

// ---------------------------------- CRF ------------------------------------
__global__ void crf_k(const float* __restrict__ em, const int* __restrict__ y,
                      const float* __restrict__ cs, const float* __restrict__ ce,
                      const float* __restrict__ tr, float* __restrict__ out) {
  __shared__ float alpha[16];
  __shared__ float trs[256];
  const int lane = threadIdx.x;
  const int i = lane & 15, jg = lane >> 4;

  for (int k = lane; k < 256; k += 64) trs[k] = tr[k];
  __syncthreads();

  float np = 0.f;
  for (int s = lane; s < 256; s += 64) np += em[s * 16 + y[s]];
  for (int s = lane + 1; s < 256; s += 64) np += trs[y[s - 1] * 16 + y[s]];
#pragma unroll
  for (int off = 32; off > 0; off >>= 1) np += __shfl_down(np, off, 64);

  if (lane < 16) alpha[lane] = cs[lane] + em[lane];
  __syncthreads();

  for (int s = 1; s < 256; ++s) {
    const float* e = em + s * 16;
    float v[4];
#pragma unroll
    for (int jj = 0; jj < 4; ++jj) v[jj] = alpha[i] + trs[i * 16 + (jj * 4 + jg)];
    float res[4];
#pragma unroll
    for (int jj = 0; jj < 4; ++jj) {
      float m = v[jj];
      m = fmaxf(m, __shfl_xor(m, 1, 64));
      m = fmaxf(m, __shfl_xor(m, 2, 64));
      m = fmaxf(m, __shfl_xor(m, 4, 64));
      m = fmaxf(m, __shfl_xor(m, 8, 64));
      float ex = __expf(v[jj] - m);
      ex += __shfl_xor(ex, 1, 64);
      ex += __shfl_xor(ex, 2, 64);
      ex += __shfl_xor(ex, 4, 64);
      ex += __shfl_xor(ex, 8, 64);
      res[jj] = m + __logf(ex) + e[jj * 4 + jg];
    }
#pragma unroll
    for (int jj = 0; jj < 4; ++jj)
      if (i == 0) alpha[jj * 4 + jg] = res[jj];
  }

  float v = (lane < 16) ? (alpha[lane] + ce[lane]) : -3.0e38f;
  float m = v;
#pragma unroll
  for (int off = 32; off > 0; off >>= 1) m = fmaxf(m, __shfl_xor(m, off, 64));
  float ex = __expf(v - m);
#pragma unroll
  for (int off = 32; off > 0; off >>= 1) ex += __shfl_xor(ex, off, 64);
  float denom = m + __logf(ex);

  if (lane == 0) {
    float num = np + cs[y[0]] + ce[y[255]];
    out[0] = num - denom;
  }
}

// ------------------------------ orchestration ------------------------------
extern "C" void kernel_launch(void* const* d_in, const int* in_sizes, int n_in,
                              void* d_out, int out_size, void* d_ws, size_t ws_size,
                              hipStream_t stream) {
  const float* x = (const float*)d_in[0];
  const int* y = (const int*)d_in[1];
  const float* w_ih_f = (const float*)d_in[3];
  const float* w_hh_f = (const float*)d_in[4];
  const float* b_f = (const float*)d_in[5];
  const float* w_ih_r = (const float*)d_in[6];
  const float* w_hh_r = (const float*)d_in[7];
  const float* b_r = (const float*)d_in[8];
  const float* w_ih_s = (const float*)d_in[9];
  const float* w_hh_s = (const float*)d_in[10];
  const float* b_s = (const float*)d_in[11];
  const float* lin_w = (const float*)d_in[12];
  const float* lin_b = (const float*)d_in[13];
  const float* crf_s = (const float*)d_in[14];
  const float* crf_e = (const float*)d_in[15];
  const float* crf_t = (const float*)d_in[16];

  char* ws = (char*)d_ws;
  size_t off = 0;
  auto take = [&](size_t bytes) {
    void* p = ws + off;
    off += (bytes + 255) & ~(size_t)255;
    return p;
  };
  bf16_t* Wx  = (bf16_t*)take((size_t)2048 * 768 * 2);
  bf16_t* Whh = (bf16_t*)take((size_t)2 * 1024 * 256 * 2);
  bf16_t* Wsi = (bf16_t*)take((size_t)2048 * 512 * 2);
  bf16_t* Wsh = (bf16_t*)take((size_t)2048 * 512 * 2);
  bf16_t* gx  = (bf16_t*)take((size_t)32768 * 2048 * 2);
  bf16_t* xb  = (bf16_t*)take((size_t)32768 * 768 * 2);   // 48MB region
  float* hT   = (float*)take((size_t)256 * 512 * 4);
  float* em   = (float*)take((size_t)4096 * 4);
  bf16_t* gs = gx;       // gx dead after lstm_fr
  bf16_t* hcat = xb;     // xb dead after gemm1
  // dead tail of xb region after gemm1 consumes it (sequential stream order)
  char* tail = (char*)xb + 33554432;
  bf16_t* hb_fr = (bf16_t*)tail;                 // 2*2*256*256*2 = 512KB
  bf16_t* hb_s  = (bf16_t*)(tail + 524288);      // 2*256*512*2   = 512KB
  unsigned* flags_fr = (unsigned*)(tail + 1048576);         // 2048 uints
  unsigned* flags_s  = (unsigned*)(tail + 1048576 + 8192);  // 2048 uints
  (void)ws_size; (void)in_sizes; (void)n_in; (void)out_size;

  // phase 1: converts
  cvt4<<<2048, 256, 0, stream>>>(x, xb, 32768 * 768 / 4);
  cvt4<<<64, 256, 0, stream>>>(w_ih_f, Wx, 786432 / 4);
  cvt4<<<64, 256, 0, stream>>>(w_ih_r, Wx + 786432, 786432 / 4);
  cvt4<<<32, 256, 0, stream>>>(w_hh_f, Whh, 262144 / 4);
  cvt4<<<32, 256, 0, stream>>>(w_hh_r, Whh + 262144, 262144 / 4);
  cvt4<<<64, 256, 0, stream>>>(w_ih_s, Wsi, 1048576 / 4);
  cvt4<<<64, 256, 0, stream>>>(w_hh_s, Wsh, 1048576 / 4);

  // phase 2: input gates for fwd+rev   (M=32768, N=2048, K=768)
  gemm_bt<<<4096, 256, 0, stream>>>(xb, Wx, gx, 32768, 2048, 768);

  // flags live in xb tail — init only after gemm1 is done with xb
  init_bar<<<16, 256, 0, stream>>>(flags_fr);

  // phase 3: fwd/rev recurrences -> h_cat
  lstm_fr<<<128, 256, 0, stream>>>(gx, Whh, b_f, b_r, hcat, hb_fr, flags_fr);

  // phase 4: sentence input gates     (M=32768, N=2048, K=512)
  gemm_bt<<<4096, 256, 0, stream>>>(hcat, Wsi, gs, 32768, 2048, 512);

  // phase 5: sentence recurrence -> hT
  lstm_s<<<128, 256, 0, stream>>>(gs, Wsh, b_s, hT, hb_s, flags_s);

  // phase 6: emissions + CRF
  emis_k<<<16, 256, 0, stream>>>(hT, lin_w, lin_b, em);
  crf_k<<<1, 64, 0, stream>>>(em, y, crf_s, crf_e, crf_t, (float*)d_out);
}

// Round 4
// 6106.031 us; speedup vs baseline: 1.0796x; 1.0796x over previous
//
#include <hip/hip_runtime.h>
#include <hip/hip_bf16.h>
#include <stdint.h>

// ---------------------------------------------------------------------------
// BiLSTM (H=256, fwd+rev) -> sentence LSTM (512->512) -> linear -> CRF(16)
// Round 4: R3 dataflow, fixed sync plumbing.
//   - ONE progress counter per sync group (fr: 4 blocks, s: 16 blocks),
//     +1 per wave with RELEASE (drains only that wave's 8B hb store)
//   - consumers poll with LANE 0 ONLY + s_sleep backoff (1 L3 req/iter/wave,
//     was 64) -> no fabric congestion, no livelock outliers
//   - h_cat scattered HBM stores issued AFTER the release: off critical path
// ---------------------------------------------------------------------------

typedef __bf16 bf16_t;
typedef __bf16 bf16x8 __attribute__((ext_vector_type(8)));
typedef __bf16 bf16x4v __attribute__((ext_vector_type(4)));
typedef float f32x4 __attribute__((ext_vector_type(4)));

#define MFMA_BF16(a, b, c) __builtin_amdgcn_mfma_f32_16x16x32_bf16((a), (b), (c), 0, 0, 0)

__device__ __forceinline__ float sigm_(float x) { return 1.f / (1.f + __expf(-x)); }
__device__ __forceinline__ float tanh_(float x) {
  x = fminf(20.f, fmaxf(-20.f, x));
  float e = __expf(-2.f * x);
  return (1.f - e) / (1.f + e);
}

__device__ __forceinline__ unsigned long long aload8(const unsigned long long* p) {
  return __hip_atomic_load(p, __ATOMIC_RELAXED, __HIP_MEMORY_SCOPE_AGENT);
}
__device__ __forceinline__ void astore8(unsigned long long* p, unsigned long long v) {
  __hip_atomic_store(p, v, __ATOMIC_RELAXED, __HIP_MEMORY_SCOPE_AGENT);
}

// lane-0-only acquire spin; whole wave blocks on the divergent branch.
__device__ __forceinline__ void wait_cnt(const unsigned* cnt, unsigned tgt) {
  if ((threadIdx.x & 63) == 0) {
    while (__hip_atomic_load(cnt, __ATOMIC_ACQUIRE, __HIP_MEMORY_SCOPE_AGENT) < tgt)
      __builtin_amdgcn_s_sleep(2);
  }
  __asm__ __volatile__("" ::: "memory");   // no compiler reordering across the spin
}

union U16 { struct { unsigned long long a, b; } s; bf16x8 v; };
union U8  { bf16x4v v; unsigned long long u; };

__global__ void init_bar(unsigned* flags) {
  int i = blockIdx.x * 256 + threadIdx.x;
  if (i < 2048) flags[i] = 0u;
}

// ---------------------------- fp32 -> bf16 convert -------------------------
__global__ void cvt4(const float* __restrict__ in, bf16_t* __restrict__ out, int n4) {
  int i = blockIdx.x * blockDim.x + threadIdx.x;
  int stride = gridDim.x * blockDim.x;
  for (; i < n4; i += stride) {
    float4 v = ((const float4*)in)[i];
    bf16x4v o;
    o.x = (bf16_t)v.x; o.y = (bf16_t)v.y; o.z = (bf16_t)v.z; o.w = (bf16_t)v.w;
    ((bf16x4v*)out)[i] = o;
  }
}

// ------------------------------- bf16 GEMM ---------------------------------
__global__ void __launch_bounds__(256, 2)
gemm_bt(const bf16_t* __restrict__ A, const bf16_t* __restrict__ B,
        bf16_t* __restrict__ C, int M, int N, int K) {
  const int tid = threadIdx.x;
  const int w = tid >> 6, lane = tid & 63, quad = lane >> 4, l15 = lane & 15;
  const int ntiles = N >> 7;
  const int m0 = (blockIdx.x / ntiles) << 7;
  const int n0 = (blockIdx.x % ntiles) << 7;
  const int wm = (w >> 1) << 6, wn = (w & 1) << 6;

  __shared__ bf16_t As[128 * 72];
  __shared__ bf16_t Bs[128 * 72];

  const f32x4 z4 = {0.f, 0.f, 0.f, 0.f};
  f32x4 acc[4][4];
#pragma unroll
  for (int i = 0; i < 4; ++i)
#pragma unroll
    for (int j = 0; j < 4; ++j) acc[i][j] = z4;

  const int nk = K >> 6;
  for (int kt = 0; kt < nk; ++kt) {
    uint4 av[4], bv[4];
#pragma unroll
    for (int i = 0; i < 4; ++i) {
      int cid = tid + i * 256;
      int r = cid >> 3, c = cid & 7;
      av[i] = *(const uint4*)&A[(size_t)(m0 + r) * K + kt * 64 + c * 8];
      bv[i] = *(const uint4*)&B[(size_t)(n0 + r) * K + kt * 64 + c * 8];
    }
    __syncthreads();
#pragma unroll
    for (int i = 0; i < 4; ++i) {
      int cid = tid + i * 256;
      int r = cid >> 3, c = cid & 7;
      *(uint4*)&As[r * 72 + c * 8] = av[i];
      *(uint4*)&Bs[r * 72 + c * 8] = bv[i];
    }
    __syncthreads();
#pragma unroll
    for (int s = 0; s < 2; ++s) {
      bf16x8 af[4], bfr[4];
#pragma unroll
      for (int i = 0; i < 4; ++i)
        af[i] = *(const bf16x8*)&As[(wm + i * 16 + l15) * 72 + s * 32 + quad * 8];
#pragma unroll
      for (int j = 0; j < 4; ++j)
        bfr[j] = *(const bf16x8*)&Bs[(wn + j * 16 + l15) * 72 + s * 32 + quad * 8];
#pragma unroll
      for (int i = 0; i < 4; ++i)
#pragma unroll
        for (int j = 0; j < 4; ++j)
          acc[i][j] = MFMA_BF16(af[i], bfr[j], acc[i][j]);
    }
  }
#pragma unroll
  for (int i = 0; i < 4; ++i)
#pragma unroll
    for (int j = 0; j < 4; ++j)
#pragma unroll
      for (int p = 0; p < 4; ++p) {
        int row = m0 + wm + i * 16 + quad * 4 + p;
        int col = n0 + wn + j * 16 + l15;
        C[(size_t)row * N + col] = (bf16_t)acc[i][j][p];
      }
}

// ----------------------- fwd/rev LSTM recurrence ---------------------------
// 128 blocks = dir(2) x bg(16: 16 rows) x hsp(4: 64 hid). Sync group = 4.
// Group counter += 4 waves x 4 blocks = 16 per step; target 16*(t-1).
// hb layout: [par(2)][dir(2)][256 rows][256 hid] bf16.
__global__ void __launch_bounds__(256, 1)
lstm_fr(const bf16_t* __restrict__ gx, const bf16_t* __restrict__ whh,
        const float* __restrict__ b_f, const float* __restrict__ b_r,
        bf16_t* __restrict__ h_cat, bf16_t* __restrict__ hb,
        unsigned* __restrict__ flags) {
  const int tid = threadIdx.x;
  const int w = tid >> 6, lane = tid & 63, quad = lane >> 4, l15 = lane & 15;
  const int dir = blockIdx.x >> 6;
  const int bg = (blockIdx.x >> 2) & 15;
  const int hsp = blockIdx.x & 3;
  const int rows0 = bg << 4;
  const int hid0 = hsp << 6;
  unsigned* grpcnt = flags + (dir * 16 + bg) * 32;   // one counter / group, 128B apart

  __shared__ bf16_t Ws[256 * 264];   // packed row = g*64+hh, K=256 (+8 pad)
  const bf16_t* Wg = whh + (size_t)dir * 262144;
#pragma unroll
  for (int i = 0; i < 32; ++i) {
    int id = tid + i * 256;          // 8192 = 256 rows x 32 chunks(16B)
    int r = id >> 5, c = id & 31;
    int g = r >> 6, hh = r & 63;
    *(uint4*)&Ws[r * 264 + c * 8] =
        *(const uint4*)&Wg[(size_t)(g * 256 + hid0 + hh) * 256 + c * 8];
  }
  const float* bias = dir ? b_r : b_f;
  const int hid = hid0 + w * 16 + quad * 4;   // 4 consecutive hid per lane
  float br[4][4];
#pragma unroll
  for (int g = 0; g < 4; ++g)
#pragma unroll
    for (int p = 0; p < 4; ++p) br[g][p] = bias[g * 256 + hid + p];
  const int brow = rows0 + l15;
  float c4[4] = {0.f, 0.f, 0.f, 0.f};
  const f32x4 z4 = {0.f, 0.f, 0.f, 0.f};
  __syncthreads();

  for (int t = 1; t <= 128; ++t) {
    const int tt = dir ? (128 - t) : (t - 1);
    // gate prefetch: independent of flags, overlaps the poll
    const size_t gbase = ((size_t)brow * 128 + tt) * 2048 + (size_t)dir * 1024;
    bf16x4v gp[4];
#pragma unroll
    for (int g = 0; g < 4; ++g) gp[g] = *(const bf16x4v*)&gx[gbase + g * 256 + hid];

    f32x4 acc[4];
#pragma unroll
    for (int g = 0; g < 4; ++g) acc[g] = z4;

    if (t >= 2) {
      wait_cnt(grpcnt, 16u * (unsigned)(t - 1));
      const unsigned long long* hrow = (const unsigned long long*)
          (hb + (((size_t)((t & 1) ^ 1) * 2 + dir) * 256 + brow) * 256);
#pragma unroll
      for (int ks = 0; ks < 8; ++ks) {
        U16 u;
        u.s.a = aload8(hrow + ks * 8 + quad * 2);
        u.s.b = aload8(hrow + ks * 8 + quad * 2 + 1);
#pragma unroll
        for (int g = 0; g < 4; ++g) {
          bf16x8 af = *(const bf16x8*)&Ws[(g * 64 + w * 16 + l15) * 264 + ks * 32 + quad * 8];
          acc[g] = MFMA_BF16(af, u.v, acc[g]);
        }
      }
    }
    // epilogue: lane holds all 4 gates for (batch=brow, hid..hid+3)
    bf16x4v hv;
#pragma unroll
    for (int p = 0; p < 4; ++p) {
      float Pi = acc[0][p] + (float)gp[0][p] + br[0][p];
      float Pf = acc[1][p] + (float)gp[1][p] + br[1][p];
      float Pg = acc[2][p] + (float)gp[2][p] + br[2][p];
      float Po = acc[3][p] + (float)gp[3][p] + br[3][p];
      float cc = sigm_(Pf) * c4[p] + sigm_(Pi) * tanh_(Pg);
      c4[p] = cc;
      hv[p] = (bf16_t)(sigm_(Po) * tanh_(cc));
    }
    if (t < 128) {
      U8 cv; cv.v = hv;
      astore8((unsigned long long*)(hb + (((size_t)(t & 1) * 2 + dir) * 256 + brow) * 256 + hid),
              cv.u);
      if (lane == 0)   // release drains this wave's hb store only
        __hip_atomic_fetch_add(grpcnt, 1u, __ATOMIC_RELEASE, __HIP_MEMORY_SCOPE_AGENT);
    }
    // scattered HBM store AFTER release: retires in the shadow of next step
    *(bf16x4v*)&h_cat[((size_t)brow * 128 + tt) * 512 + dir * 256 + hid] = hv;
  }
}

// ------------------------ sentence LSTM recurrence -------------------------
// 128 blocks = bg(8: 32 rows) x hsp(16: 32 hid). Sync group = 16.
// Group counter += 4 waves x 16 blocks = 64 per step; target 64*(t-1).
// hb layout: [par(2)][256 rows][512 hid] bf16.
__global__ void __launch_bounds__(256, 1)
lstm_s(const bf16_t* __restrict__ gs, const bf16_t* __restrict__ wsh,
       const float* __restrict__ b_s, float* __restrict__ hT,
       bf16_t* __restrict__ hb, unsigned* __restrict__ flags) {
  const int tid = threadIdx.x;
  const int w = tid >> 6, lane = tid & 63, quad = lane >> 4, l15 = lane & 15;
  const int bg = blockIdx.x >> 4;
  const int hsp = blockIdx.x & 15;
  const int rows0 = bg << 5;
  const int hid0 = hsp << 5;
  const int nt = w & 1, hb2 = w >> 1;         // wave: batch-half, hid-half
  unsigned* grpcnt = flags + bg * 32;

  __shared__ bf16_t Ws[128 * 520];   // packed row = g*32+hh, K=512 (+8 pad)
#pragma unroll
  for (int i = 0; i < 32; ++i) {
    int id = tid + i * 256;          // 8192 = 128 rows x 64 chunks(16B)
    int r = id >> 6, c = id & 63;
    int g = r >> 5, hh = r & 31;
    *(uint4*)&Ws[r * 520 + c * 8] =
        *(const uint4*)&wsh[(size_t)(g * 512 + hid0 + hh) * 512 + c * 8];
  }
  const int hid = hid0 + hb2 * 16 + quad * 4;
  float br[4][4];
#pragma unroll
  for (int g = 0; g < 4; ++g)
#pragma unroll
    for (int p = 0; p < 4; ++p) br[g][p] = b_s[g * 512 + hid + p];
  const int brow = rows0 + nt * 16 + l15;
  float c4[4] = {0.f, 0.f, 0.f, 0.f};
  const f32x4 z4 = {0.f, 0.f, 0.f, 0.f};
  __syncthreads();

  for (int t = 1; t <= 128; ++t) {
    const size_t gbase = ((size_t)brow * 128 + (t - 1)) * 2048;
    bf16x4v gp[4];
#pragma unroll
    for (int g = 0; g < 4; ++g) gp[g] = *(const bf16x4v*)&gs[gbase + g * 512 + hid];

    f32x4 acc[4];
#pragma unroll
    for (int g = 0; g < 4; ++g) acc[g] = z4;

    if (t >= 2) {
      wait_cnt(grpcnt, 64u * (unsigned)(t - 1));
      const unsigned long long* hrow = (const unsigned long long*)
          (hb + ((size_t)((t & 1) ^ 1) * 256 + brow) * 512);
#pragma unroll
      for (int ks = 0; ks < 16; ++ks) {
        U16 u;
        u.s.a = aload8(hrow + ks * 8 + quad * 2);
        u.s.b = aload8(hrow + ks * 8 + quad * 2 + 1);
#pragma unroll
        for (int g = 0; g < 4; ++g) {
          bf16x8 af = *(const bf16x8*)&Ws[(g * 32 + hb2 * 16 + l15) * 520 + ks * 32 + quad * 8];
          acc[g] = MFMA_BF16(af, u.v, acc[g]);
        }
      }
    }
    bf16x4v hv;
    float hf[4];
#pragma unroll
    for (int p = 0; p < 4; ++p) {
      float Pi = acc[0][p] + (float)gp[0][p] + br[0][p];
      float Pf = acc[1][p] + (float)gp[1][p] + br[1][p];
      float Pg = acc[2][p] + (float)gp[2][p] + br[2][p];
      float Po = acc[3][p] + (float)gp[3][p] + br[3][p];
      float cc = sigm_(Pf) * c4[p] + sigm_(Pi) * tanh_(Pg);
      c4[p] = cc;
      hf[p] = sigm_(Po) * tanh_(cc);
      hv[p] = (bf16_t)hf[p];
    }
    if (t < 128) {
      U8 cv; cv.v = hv;
      astore8((unsigned long long*)(hb + ((size_t)(t & 1) * 256 + brow) * 512 + hid), cv.u);
      if (lane == 0)
        __hip_atomic_fetch_add(grpcnt, 1u, __ATOMIC_RELEASE, __HIP_MEMORY_SCOPE_AGENT);
    } else {
      *(float4*)&hT[(size_t)brow * 512 + hid] = make_float4(hf[0], hf[1], hf[2], hf[3]);
    }
  }
}

// ------------------------------- emissions ---------------------------------
__global__ void emis_k(const float* __restrict__ hT, const float* __restrict__ lin_w,
                       const float* __restrict__ lin_b, float* __restrict__ em) {
  const int idx = blockIdx.x * 256 + threadIdx.x;
  const int s = idx >> 4, c = idx & 15;
  const float4* h4 = (const float4*)(hT + (size_t)s * 512);
  const float4* w4 = (const float4*)(lin_w + (size_t)c * 512);
  float acc = lin_b[c];
  for (int k = 0; k < 128; ++k) {
    float4 a = h4[k], b = w4[k];
    acc += a.x * b.x + a.y * b.y + a.z * b.z + a.w * b.w;
  }
  em[idx] = acc;
}

// ---------------------------------- CRF ------------------------------------
__global__ void crf_k(const float* __restrict__ em, const int* __restrict__ y,
                      const float* __restrict__ cs, const float* __restrict__ ce,
                      const float* __restrict__ tr, float* __restrict__ out) {
  __shared__ float alpha[16];
  __shared__ float trs[256];
  const int lane = threadIdx.x;
  const int i = lane & 15, jg = lane >> 4;

  for (int k = lane; k < 256; k += 64) trs[k] = tr[k];
  __syncthreads();

  float np = 0.f;
  for (int s = lane; s < 256; s += 64) np += em[s * 16 + y[s]];
  for (int s = lane + 1; s < 256; s += 64) np += trs[y[s - 1] * 16 + y[s]];
#pragma unroll
  for (int off = 32; off > 0; off >>= 1) np += __shfl_down(np, off, 64);

  if (lane < 16) alpha[lane] = cs[lane] + em[lane];
  __syncthreads();

  for (int s = 1; s < 256; ++s) {
    const float* e = em + s * 16;
    float v[4];
#pragma unroll
    for (int jj = 0; jj < 4; ++jj) v[jj] = alpha[i] + trs[i * 16 + (jj * 4 + jg)];
    float res[4];
#pragma unroll
    for (int jj = 0; jj < 4; ++jj) {
      float m = v[jj];
      m = fmaxf(m, __shfl_xor(m, 1, 64));
      m = fmaxf(m, __shfl_xor(m, 2, 64));
      m = fmaxf(m, __shfl_xor(m, 4, 64));
      m = fmaxf(m, __shfl_xor(m, 8, 64));
      float ex = __expf(v[jj] - m);
      ex += __shfl_xor(ex, 1, 64);
      ex += __shfl_xor(ex, 2, 64);
      ex += __shfl_xor(ex, 4, 64);
      ex += __shfl_xor(ex, 8, 64);
      res[jj] = m + __logf(ex) + e[jj * 4 + jg];
    }
#pragma unroll
    for (int jj = 0; jj < 4; ++jj)
      if (i == 0) alpha[jj * 4 + jg] = res[jj];
  }

  float v = (lane < 16) ? (alpha[lane] + ce[lane]) : -3.0e38f;
  float m = v;
#pragma unroll
  for (int off = 32; off > 0; off >>= 1) m = fmaxf(m, __shfl_xor(m, off, 64));
  float ex = __expf(v - m);
#pragma unroll
  for (int off = 32; off > 0; off >>= 1) ex += __shfl_xor(ex, off, 64);
  float denom = m + __logf(ex);

  if (lane == 0) {
    float num = np + cs[y[0]] + ce[y[255]];
    out[0] = num - denom;
  }
}

// ------------------------------ orchestration ------------------------------
extern "C" void kernel_launch(void* const* d_in, const int* in_sizes, int n_in,
                              void* d_out, int out_size, void* d_ws, size_t ws_size,
                              hipStream_t stream) {
  const float* x = (const float*)d_in[0];
  const int* y = (const int*)d_in[1];
  const float* w_ih_f = (const float*)d_in[3];
  const float* w_hh_f = (const float*)d_in[4];
  const float* b_f = (const float*)d_in[5];
  const float* w_ih_r = (const float*)d_in[6];
  const float* w_hh_r = (const float*)d_in[7];
  const float* b_r = (const float*)d_in[8];
  const float* w_ih_s = (const float*)d_in[9];
  const float* w_hh_s = (const float*)d_in[10];
  const float* b_s = (const float*)d_in[11];
  const float* lin_w = (const float*)d_in[12];
  const float* lin_b = (const float*)d_in[13];
  const float* crf_s = (const float*)d_in[14];
  const float* crf_e = (const float*)d_in[15];
  const float* crf_t = (const float*)d_in[16];

  char* ws = (char*)d_ws;
  size_t off = 0;
  auto take = [&](size_t bytes) {
    void* p = ws + off;
    off += (bytes + 255) & ~(size_t)255;
    return p;
  };
  bf16_t* Wx  = (bf16_t*)take((size_t)2048 * 768 * 2);
  bf16_t* Whh = (bf16_t*)take((size_t)2 * 1024 * 256 * 2);
  bf16_t* Wsi = (bf16_t*)take((size_t)2048 * 512 * 2);
  bf16_t* Wsh = (bf16_t*)take((size_t)2048 * 512 * 2);
  bf16_t* gx  = (bf16_t*)take((size_t)32768 * 2048 * 2);
  bf16_t* xb  = (bf16_t*)take((size_t)32768 * 768 * 2);   // 48MB region
  float* hT   = (float*)take((size_t)256 * 512 * 4);
  float* em   = (float*)take((size_t)4096 * 4);
  bf16_t* gs = gx;       // gx dead after lstm_fr
  bf16_t* hcat = xb;     // xb dead after gemm1
  // dead tail of xb region after gemm1 consumes it
  char* tail = (char*)xb + 33554432;
  bf16_t* hb_fr = (bf16_t*)tail;                 // 2*2*256*256*2 = 512KB
  bf16_t* hb_s  = (bf16_t*)(tail + 524288);      // 2*256*512*2   = 512KB
  unsigned* flags_fr = (unsigned*)(tail + 1048576);         // 32 grp x 32 uints
  unsigned* flags_s  = (unsigned*)(tail + 1048576 + 4096);  // 8 grp x 32 uints
  (void)ws_size; (void)in_sizes; (void)n_in; (void)out_size;

  // phase 1: converts
  cvt4<<<2048, 256, 0, stream>>>(x, xb, 32768 * 768 / 4);
  cvt4<<<64, 256, 0, stream>>>(w_ih_f, Wx, 786432 / 4);
  cvt4<<<64, 256, 0, stream>>>(w_ih_r, Wx + 786432, 786432 / 4);
  cvt4<<<32, 256, 0, stream>>>(w_hh_f, Whh, 262144 / 4);
  cvt4<<<32, 256, 0, stream>>>(w_hh_r, Whh + 262144, 262144 / 4);
  cvt4<<<64, 256, 0, stream>>>(w_ih_s, Wsi, 1048576 / 4);
  cvt4<<<64, 256, 0, stream>>>(w_hh_s, Wsh, 1048576 / 4);

  // phase 2: input gates for fwd+rev   (M=32768, N=2048, K=768)
  gemm_bt<<<4096, 256, 0, stream>>>(xb, Wx, gx, 32768, 2048, 768);

  // flags live in xb tail — init only after gemm1 is done with xb
  init_bar<<<8, 256, 0, stream>>>(flags_fr);

  // phase 3: fwd/rev recurrences -> h_cat
  lstm_fr<<<128, 256, 0, stream>>>(gx, Whh, b_f, b_r, hcat, hb_fr, flags_fr);

  // phase 4: sentence input gates     (M=32768, N=2048, K=512)
  gemm_bt<<<4096, 256, 0, stream>>>(hcat, Wsi, gs, 32768, 2048, 512);

  // phase 5: sentence recurrence -> hT
  lstm_s<<<128, 256, 0, stream>>>(gs, Wsh, b_s, hT, hb_s, flags_s);

  // phase 6: emissions + CRF
  emis_k<<<16, 256, 0, stream>>>(hT, lin_w, lin_b, em);
  crf_k<<<1, 64, 0, stream>>>(em, y, crf_s, crf_e, crf_t, (float*)d_out);
}

// Round 5
// 3198.178 us; speedup vs baseline: 2.0611x; 1.9092x over previous
//
#include <hip/hip_runtime.h>
#include <hip/hip_bf16.h>
#include <stdint.h>

// ---------------------------------------------------------------------------
// BiLSTM (H=256, fwd+rev) -> sentence LSTM (512->512) -> linear -> CRF(16)
// Round 5: R4 dataflow, sync rebuilt with ZERO atomic RMWs and ZERO acquires.
//   - per-block flag = step number, atomic STORE by one lane after
//     __syncthreads() (its vmcnt(0) drain publishes all waves' h-stores)
//   - consumers poll flag lines with RELAXED atomic loads (no buffer_inv,
//     no L2 invalidation -> gx/gs stay cached; no RMW serialization)
//   - h exchange via relaxed agent-scope 8B atomics (L3-coherent by construction)
// ---------------------------------------------------------------------------

typedef __bf16 bf16_t;
typedef __bf16 bf16x8 __attribute__((ext_vector_type(8)));
typedef __bf16 bf16x4v __attribute__((ext_vector_type(4)));
typedef float f32x4 __attribute__((ext_vector_type(4)));

#define MFMA_BF16(a, b, c) __builtin_amdgcn_mfma_f32_16x16x32_bf16((a), (b), (c), 0, 0, 0)

__device__ __forceinline__ float sigm_(float x) { return 1.f / (1.f + __expf(-x)); }
__device__ __forceinline__ float tanh_(float x) {
  x = fminf(20.f, fmaxf(-20.f, x));
  float e = __expf(-2.f * x);
  return (1.f - e) / (1.f + e);
}

__device__ __forceinline__ unsigned long long aload8(const unsigned long long* p) {
  return __hip_atomic_load(p, __ATOMIC_RELAXED, __HIP_MEMORY_SCOPE_AGENT);
}
__device__ __forceinline__ void astore8(unsigned long long* p, unsigned long long v) {
  __hip_atomic_store(p, v, __ATOMIC_RELAXED, __HIP_MEMORY_SCOPE_AGENT);
}

// Poll NG flag lines (stride 32 uints) until all >= tgt. RELAXED loads only.
template <int NG>
__device__ __forceinline__ void wait_flags(const unsigned* base, unsigned tgt) {
  const int lane = threadIdx.x & 63;
  for (;;) {
    unsigned f = tgt;
    if (lane < NG)
      f = __hip_atomic_load(base + lane * 32, __ATOMIC_RELAXED, __HIP_MEMORY_SCOPE_AGENT);
    if (__all((int)(f >= tgt))) break;
    __builtin_amdgcn_s_sleep(1);
  }
  __asm__ __volatile__("" ::: "memory");   // no compiler reordering across the spin
}

union U16 { struct { unsigned long long a, b; } s; bf16x8 v; };
union U8  { bf16x4v v; unsigned long long u; };

__global__ void init_bar(unsigned* flags) {
  int i = blockIdx.x * 256 + threadIdx.x;
  flags[i] = 0u;   // grid sized to cover exactly the flag region
}

// ---------------------------- fp32 -> bf16 convert -------------------------
__global__ void cvt4(const float* __restrict__ in, bf16_t* __restrict__ out, int n4) {
  int i = blockIdx.x * blockDim.x + threadIdx.x;
  int stride = gridDim.x * blockDim.x;
  for (; i < n4; i += stride) {
    float4 v = ((const float4*)in)[i];
    bf16x4v o;
    o.x = (bf16_t)v.x; o.y = (bf16_t)v.y; o.z = (bf16_t)v.z; o.w = (bf16_t)v.w;
    ((bf16x4v*)out)[i] = o;
  }
}

// ------------------------------- bf16 GEMM ---------------------------------
__global__ void __launch_bounds__(256, 2)
gemm_bt(const bf16_t* __restrict__ A, const bf16_t* __restrict__ B,
        bf16_t* __restrict__ C, int M, int N, int K) {
  const int tid = threadIdx.x;
  const int w = tid >> 6, lane = tid & 63, quad = lane >> 4, l15 = lane & 15;
  const int ntiles = N >> 7;
  const int m0 = (blockIdx.x / ntiles) << 7;
  const int n0 = (blockIdx.x % ntiles) << 7;
  const int wm = (w >> 1) << 6, wn = (w & 1) << 6;

  __shared__ bf16_t As[128 * 72];
  __shared__ bf16_t Bs[128 * 72];

  const f32x4 z4 = {0.f, 0.f, 0.f, 0.f};
  f32x4 acc[4][4];
#pragma unroll
  for (int i = 0; i < 4; ++i)
#pragma unroll
    for (int j = 0; j < 4; ++j) acc[i][j] = z4;

  const int nk = K >> 6;
  for (int kt = 0; kt < nk; ++kt) {
    uint4 av[4], bv[4];
#pragma unroll
    for (int i = 0; i < 4; ++i) {
      int cid = tid + i * 256;
      int r = cid >> 3, c = cid & 7;
      av[i] = *(const uint4*)&A[(size_t)(m0 + r) * K + kt * 64 + c * 8];
      bv[i] = *(const uint4*)&B[(size_t)(n0 + r) * K + kt * 64 + c * 8];
    }
    __syncthreads();
#pragma unroll
    for (int i = 0; i < 4; ++i) {
      int cid = tid + i * 256;
      int r = cid >> 3, c = cid & 7;
      *(uint4*)&As[r * 72 + c * 8] = av[i];
      *(uint4*)&Bs[r * 72 + c * 8] = bv[i];
    }
    __syncthreads();
#pragma unroll
    for (int s = 0; s < 2; ++s) {
      bf16x8 af[4], bfr[4];
#pragma unroll
      for (int i = 0; i < 4; ++i)
        af[i] = *(const bf16x8*)&As[(wm + i * 16 + l15) * 72 + s * 32 + quad * 8];
#pragma unroll
      for (int j = 0; j < 4; ++j)
        bfr[j] = *(const bf16x8*)&Bs[(wn + j * 16 + l15) * 72 + s * 32 + quad * 8];
#pragma unroll
      for (int i = 0; i < 4; ++i)
#pragma unroll
        for (int j = 0; j < 4; ++j)
          acc[i][j] = MFMA_BF16(af[i], bfr[j], acc[i][j]);
    }
  }
#pragma unroll
  for (int i = 0; i < 4; ++i)
#pragma unroll
    for (int j = 0; j < 4; ++j)
#pragma unroll
      for (int p = 0; p < 4; ++p) {
        int row = m0 + wm + i * 16 + quad * 4 + p;
        int col = n0 + wn + j * 16 + l15;
        C[(size_t)row * N + col] = (bf16_t)acc[i][j][p];
      }
}

// ----------------------- fwd/rev LSTM recurrence ---------------------------
// 128 blocks = dir(2) x bg(16: 16 rows) x hsp(4: 64 hid). Sync group = 4.
// Flag[group][hsp] = last published step (single writer, atomic store).
// hb layout: [par(2)][dir(2)][256 rows][256 hid] bf16.
__global__ void __launch_bounds__(256, 1)
lstm_fr(const bf16_t* __restrict__ gx, const bf16_t* __restrict__ whh,
        const float* __restrict__ b_f, const float* __restrict__ b_r,
        bf16_t* __restrict__ h_cat, bf16_t* __restrict__ hb,
        unsigned* __restrict__ flags) {
  const int tid = threadIdx.x;
  const int w = tid >> 6, lane = tid & 63, quad = lane >> 4, l15 = lane & 15;
  const int dir = blockIdx.x >> 6;
  const int bg = (blockIdx.x >> 2) & 15;
  const int hsp = blockIdx.x & 3;
  const int rows0 = bg << 4;
  const int hid0 = hsp << 6;
  unsigned* fgrp = flags + (dir * 16 + bg) * 128;   // 4 lines x 32 uints
  unsigned* fmine = fgrp + hsp * 32;

  __shared__ bf16_t Ws[256 * 264];   // packed row = g*64+hh, K=256 (+8 pad)
  const bf16_t* Wg = whh + (size_t)dir * 262144;
#pragma unroll
  for (int i = 0; i < 32; ++i) {
    int id = tid + i * 256;          // 8192 = 256 rows x 32 chunks(16B)
    int r = id >> 5, c = id & 31;
    int g = r >> 6, hh = r & 63;
    *(uint4*)&Ws[r * 264 + c * 8] =
        *(const uint4*)&Wg[(size_t)(g * 256 + hid0 + hh) * 256 + c * 8];
  }
  const float* bias = dir ? b_r : b_f;
  const int hid = hid0 + w * 16 + quad * 4;   // 4 consecutive hid per lane
  float br[4][4];
#pragma unroll
  for (int g = 0; g < 4; ++g)
#pragma unroll
    for (int p = 0; p < 4; ++p) br[g][p] = bias[g * 256 + hid + p];
  const int brow = rows0 + l15;
  float c4[4] = {0.f, 0.f, 0.f, 0.f};
  const f32x4 z4 = {0.f, 0.f, 0.f, 0.f};
  __syncthreads();

  for (int t = 1; t <= 128; ++t) {
    const int tt = dir ? (128 - t) : (t - 1);
    // gate prefetch: independent of flags, overlaps the poll
    const size_t gbase = ((size_t)brow * 128 + tt) * 2048 + (size_t)dir * 1024;
    bf16x4v gp[4];
#pragma unroll
    for (int g = 0; g < 4; ++g) gp[g] = *(const bf16x4v*)&gx[gbase + g * 256 + hid];

    f32x4 acc[4];
#pragma unroll
    for (int g = 0; g < 4; ++g) acc[g] = z4;

    if (t >= 2) {
      wait_flags<4>(fgrp, (unsigned)(t - 1));
      const unsigned long long* hrow = (const unsigned long long*)
          (hb + (((size_t)((t & 1) ^ 1) * 2 + dir) * 256 + brow) * 256);
#pragma unroll
      for (int ks = 0; ks < 8; ++ks) {
        U16 u;
        u.s.a = aload8(hrow + ks * 8 + quad * 2);
        u.s.b = aload8(hrow + ks * 8 + quad * 2 + 1);
#pragma unroll
        for (int g = 0; g < 4; ++g) {
          bf16x8 af = *(const bf16x8*)&Ws[(g * 64 + w * 16 + l15) * 264 + ks * 32 + quad * 8];
          acc[g] = MFMA_BF16(af, u.v, acc[g]);
        }
      }
    }
    // epilogue: lane holds all 4 gates for (batch=brow, hid..hid+3)
    bf16x4v hv;
#pragma unroll
    for (int p = 0; p < 4; ++p) {
      float Pi = acc[0][p] + (float)gp[0][p] + br[0][p];
      float Pf = acc[1][p] + (float)gp[1][p] + br[1][p];
      float Pg = acc[2][p] + (float)gp[2][p] + br[2][p];
      float Po = acc[3][p] + (float)gp[3][p] + br[3][p];
      float cc = sigm_(Pf) * c4[p] + sigm_(Pi) * tanh_(Pg);
      c4[p] = cc;
      hv[p] = (bf16_t)(sigm_(Po) * tanh_(cc));
    }
    if (t < 128) {
      U8 cv; cv.v = hv;
      astore8((unsigned long long*)(hb + (((size_t)(t & 1) * 2 + dir) * 256 + brow) * 256 + hid),
              cv.u);
      __syncthreads();   // vmcnt(0) drain of ALL waves' h stores, then publish
      if (tid == 0)
        __hip_atomic_store(fmine, (unsigned)t, __ATOMIC_RELEASE, __HIP_MEMORY_SCOPE_AGENT);
    }
    // scattered HBM store AFTER publish: retires in the shadow of next step
    *(bf16x4v*)&h_cat[((size_t)brow * 128 + tt) * 512 + dir * 256 + hid] = hv;
  }
}

// ------------------------ sentence LSTM recurrence -------------------------
// 128 blocks = bg(8: 32 rows) x hsp(16: 32 hid). Sync group = 16.
// hb layout: [par(2)][256 rows][512 hid] bf16.
__global__ void __launch_bounds__(256, 1)
lstm_s(const bf16_t* __restrict__ gs, const bf16_t* __restrict__ wsh,
       const float* __restrict__ b_s, float* __restrict__ hT,
       bf16_t* __restrict__ hb, unsigned* __restrict__ flags) {
  const int tid = threadIdx.x;
  const int w = tid >> 6, lane = tid & 63, quad = lane >> 4, l15 = lane & 15;
  const int bg = blockIdx.x >> 4;
  const int hsp = blockIdx.x & 15;
  const int rows0 = bg << 5;
  const int hid0 = hsp << 5;
  const int nt = w & 1, hb2 = w >> 1;         // wave: batch-half, hid-half
  unsigned* fgrp = flags + bg * 512;          // 16 lines x 32 uints
  unsigned* fmine = fgrp + hsp * 32;

  __shared__ bf16_t Ws[128 * 520];   // packed row = g*32+hh, K=512 (+8 pad)
#pragma unroll
  for (int i = 0; i < 32; ++i) {
    int id = tid + i * 256;          // 8192 = 128 rows x 64 chunks(16B)
    int r = id >> 6, c = id & 63;
    int g = r >> 5, hh = r & 31;
    *(uint4*)&Ws[r * 520 + c * 8] =
        *(const uint4*)&wsh[(size_t)(g * 512 + hid0 + hh) * 512 + c * 8];
  }
  const int hid = hid0 + hb2 * 16 + quad * 4;
  float br[4][4];
#pragma unroll
  for (int g = 0; g < 4; ++g)
#pragma unroll
    for (int p = 0; p < 4; ++p) br[g][p] = b_s[g * 512 + hid + p];
  const int brow = rows0 + nt * 16 + l15;
  float c4[4] = {0.f, 0.f, 0.f, 0.f};
  const f32x4 z4 = {0.f, 0.f, 0.f, 0.f};
  __syncthreads();

  for (int t = 1; t <= 128; ++t) {
    const size_t gbase = ((size_t)brow * 128 + (t - 1)) * 2048;
    bf16x4v gp[4];
#pragma unroll
    for (int g = 0; g < 4; ++g) gp[g] = *(const bf16x4v*)&gs[gbase + g * 512 + hid];

    f32x4 acc[4];
#pragma unroll
    for (int g = 0; g < 4; ++g) acc[g] = z4;

    if (t >= 2) {
      wait_flags<16>(fgrp, (unsigned)(t - 1));
      const unsigned long long* hrow = (const unsigned long long*)
          (hb + ((size_t)((t & 1) ^ 1) * 256 + brow) * 512);
#pragma unroll
      for (int ks = 0; ks < 16; ++ks) {
        U16 u;
        u.s.a = aload8(hrow + ks * 8 + quad * 2);
        u.s.b = aload8(hrow + ks * 8 + quad * 2 + 1);
#pragma unroll
        for (int g = 0; g < 4; ++g) {
          bf16x8 af = *(const bf16x8*)&Ws[(g * 32 + hb2 * 16 + l15) * 520 + ks * 32 + quad * 8];
          acc[g] = MFMA_BF16(af, u.v, acc[g]);
        }
      }
    }
    bf16x4v hv;
    float hf[4];
#pragma unroll
    for (int p = 0; p < 4; ++p) {
      float Pi = acc[0][p] + (float)gp[0][p] + br[0][p];
      float Pf = acc[1][p] + (float)gp[1][p] + br[1][p];
      float Pg = acc[2][p] + (float)gp[2][p] + br[2][p];
      float Po = acc[3][p] + (float)gp[3][p] + br[3][p];
      float cc = sigm_(Pf) * c4[p] + sigm_(Pi) * tanh_(Pg);
      c4[p] = cc;
      hf[p] = sigm_(Po) * tanh_(cc);
      hv[p] = (bf16_t)hf[p];
    }
    if (t < 128) {
      U8 cv; cv.v = hv;
      astore8((unsigned long long*)(hb + ((size_t)(t & 1) * 256 + brow) * 512 + hid), cv.u);
      __syncthreads();
      if (tid == 0)
        __hip_atomic_store(fmine, (unsigned)t, __ATOMIC_RELEASE, __HIP_MEMORY_SCOPE_AGENT);
    } else {
      *(float4*)&hT[(size_t)brow * 512 + hid] = make_float4(hf[0], hf[1], hf[2], hf[3]);
    }
  }
}

// ------------------------------- emissions ---------------------------------
__global__ void emis_k(const float* __restrict__ hT, const float* __restrict__ lin_w,
                       const float* __restrict__ lin_b, float* __restrict__ em) {
  const int idx = blockIdx.x * 256 + threadIdx.x;
  const int s = idx >> 4, c = idx & 15;
  const float4* h4 = (const float4*)(hT + (size_t)s * 512);
  const float4* w4 = (const float4*)(lin_w + (size_t)c * 512);
  float acc = lin_b[c];
  for (int k = 0; k < 128; ++k) {
    float4 a = h4[k], b = w4[k];
    acc += a.x * b.x + a.y * b.y + a.z * b.z + a.w * b.w;
  }
  em[idx] = acc;
}

// ---------------------------------- CRF ------------------------------------
__global__ void crf_k(const float* __restrict__ em, const int* __restrict__ y,
                      const float* __restrict__ cs, const float* __restrict__ ce,
                      const float* __restrict__ tr, float* __restrict__ out) {
  __shared__ float alpha[16];
  __shared__ float trs[256];
  const int lane = threadIdx.x;
  const int i = lane & 15, jg = lane >> 4;

  for (int k = lane; k < 256; k += 64) trs[k] = tr[k];
  __syncthreads();

  float np = 0.f;
  for (int s = lane; s < 256; s += 64) np += em[s * 16 + y[s]];
  for (int s = lane + 1; s < 256; s += 64) np += trs[y[s - 1] * 16 + y[s]];
#pragma unroll
  for (int off = 32; off > 0; off >>= 1) np += __shfl_down(np, off, 64);

  if (lane < 16) alpha[lane] = cs[lane] + em[lane];
  __syncthreads();

  for (int s = 1; s < 256; ++s) {
    const float* e = em + s * 16;
    float v[4];
#pragma unroll
    for (int jj = 0; jj < 4; ++jj) v[jj] = alpha[i] + trs[i * 16 + (jj * 4 + jg)];
    float res[4];
#pragma unroll
    for (int jj = 0; jj < 4; ++jj) {
      float m = v[jj];
      m = fmaxf(m, __shfl_xor(m, 1, 64));
      m = fmaxf(m, __shfl_xor(m, 2, 64));
      m = fmaxf(m, __shfl_xor(m, 4, 64));
      m = fmaxf(m, __shfl_xor(m, 8, 64));
      float ex = __expf(v[jj] - m);
      ex += __shfl_xor(ex, 1, 64);
      ex += __shfl_xor(ex, 2, 64);
      ex += __shfl_xor(ex, 4, 64);
      ex += __shfl_xor(ex, 8, 64);
      res[jj] = m + __logf(ex) + e[jj * 4 + jg];
    }
#pragma unroll
    for (int jj = 0; jj < 4; ++jj)
      if (i == 0) alpha[jj * 4 + jg] = res[jj];
  }

  float v = (lane < 16) ? (alpha[lane] + ce[lane]) : -3.0e38f;
  float m = v;
#pragma unroll
  for (int off = 32; off > 0; off >>= 1) m = fmaxf(m, __shfl_xor(m, off, 64));
  float ex = __expf(v - m);
#pragma unroll
  for (int off = 32; off > 0; off >>= 1) ex += __shfl_xor(ex, off, 64);
  float denom = m + __logf(ex);

  if (lane == 0) {
    float num = np + cs[y[0]] + ce[y[255]];
    out[0] = num - denom;
  }
}

// ------------------------------ orchestration ------------------------------
extern "C" void kernel_launch(void* const* d_in, const int* in_sizes, int n_in,
                              void* d_out, int out_size, void* d_ws, size_t ws_size,
                              hipStream_t stream) {
  const float* x = (const float*)d_in[0];
  const int* y = (const int*)d_in[1];
  const float* w_ih_f = (const float*)d_in[3];
  const float* w_hh_f = (const float*)d_in[4];
  const float* b_f = (const float*)d_in[5];
  const float* w_ih_r = (const float*)d_in[6];
  const float* w_hh_r = (const float*)d_in[7];
  const float* b_r = (const float*)d_in[8];
  const float* w_ih_s = (const float*)d_in[9];
  const float* w_hh_s = (const float*)d_in[10];
  const float* b_s = (const float*)d_in[11];
  const float* lin_w = (const float*)d_in[12];
  const float* lin_b = (const float*)d_in[13];
  const float* crf_s = (const float*)d_in[14];
  const float* crf_e = (const float*)d_in[15];
  const float* crf_t = (const float*)d_in[16];

  char* ws = (char*)d_ws;
  size_t off = 0;
  auto take = [&](size_t bytes) {
    void* p = ws + off;
    off += (bytes + 255) & ~(size_t)255;
    return p;
  };
  bf16_t* Wx  = (bf16_t*)take((size_t)2048 * 768 * 2);
  bf16_t* Whh = (bf16_t*)take((size_t)2 * 1024 * 256 * 2);
  bf16_t* Wsi = (bf16_t*)take((size_t)2048 * 512 * 2);
  bf16_t* Wsh = (bf16_t*)take((size_t)2048 * 512 * 2);
  bf16_t* gx  = (bf16_t*)take((size_t)32768 * 2048 * 2);
  bf16_t* xb  = (bf16_t*)take((size_t)32768 * 768 * 2);   // 48MB region
  float* hT   = (float*)take((size_t)256 * 512 * 4);
  float* em   = (float*)take((size_t)4096 * 4);
  bf16_t* gs = gx;       // gx dead after lstm_fr
  bf16_t* hcat = xb;     // xb dead after gemm1
  // dead tail of xb region after gemm1 consumes it
  char* tail = (char*)xb + 33554432;
  bf16_t* hb_fr = (bf16_t*)tail;                 // 2*2*256*256*2 = 512KB
  bf16_t* hb_s  = (bf16_t*)(tail + 524288);      // 2*256*512*2   = 512KB
  unsigned* flags_fr = (unsigned*)(tail + 1048576);          // 32 grp x 128 uints
  unsigned* flags_s  = (unsigned*)(tail + 1048576 + 16384);  // 8 grp x 512 uints
  (void)ws_size; (void)in_sizes; (void)n_in; (void)out_size;

  // phase 1: converts
  cvt4<<<2048, 256, 0, stream>>>(x, xb, 32768 * 768 / 4);
  cvt4<<<64, 256, 0, stream>>>(w_ih_f, Wx, 786432 / 4);
  cvt4<<<64, 256, 0, stream>>>(w_ih_r, Wx + 786432, 786432 / 4);
  cvt4<<<32, 256, 0, stream>>>(w_hh_f, Whh, 262144 / 4);
  cvt4<<<32, 256, 0, stream>>>(w_hh_r, Whh + 262144, 262144 / 4);
  cvt4<<<64, 256, 0, stream>>>(w_ih_s, Wsi, 1048576 / 4);
  cvt4<<<64, 256, 0, stream>>>(w_hh_s, Wsh, 1048576 / 4);

  // phase 2: input gates for fwd+rev   (M=32768, N=2048, K=768)
  gemm_bt<<<4096, 256, 0, stream>>>(xb, Wx, gx, 32768, 2048, 768);

  // flags live in xb tail — init only after gemm1 is done with xb
  // (zero both arrays: 4096 + 4096 uints = 32 blocks x 256)
  init_bar<<<32, 256, 0, stream>>>(flags_fr);

  // phase 3: fwd/rev recurrences -> h_cat
  lstm_fr<<<128, 256, 0, stream>>>(gx, Whh, b_f, b_r, hcat, hb_fr, flags_fr);

  // phase 4: sentence input gates     (M=32768, N=2048, K=512)
  gemm_bt<<<4096, 256, 0, stream>>>(hcat, Wsi, gs, 32768, 2048, 512);

  // phase 5: sentence recurrence -> hT
  lstm_s<<<128, 256, 0, stream>>>(gs, Wsh, b_s, hT, hb_s, flags_s);

  // phase 6: emissions + CRF
  emis_k<<<16, 256, 0, stream>>>(hT, lin_w, lin_b, em);
  crf_k<<<1, 64, 0, stream>>>(em, y, crf_s, crf_e, crf_t, (float*)d_out);
}

// Round 6
// 3126.584 us; speedup vs baseline: 2.1083x; 1.0229x over previous
//
#include <hip/hip_runtime.h>
#include <hip/hip_bf16.h>
#include <stdint.h>

// ---------------------------------------------------------------------------
// BiLSTM (H=256, fwd+rev) -> sentence LSTM (512->512) -> linear -> CRF(16)
// Round 6: R5 sync semantics (single-writer flag stores, relaxed polls,
// no RMW, no acquire), with per-step overheads cut:
//   - wave 0 polls, other waves wait at __syncthreads (poll traffic /4)
//   - s_sleep(2) backoff (poll rounds /2)
//   - lstm_fr: h_cat staged in a 16KB LDS ring, dumped as coalesced
//     128B-line bursts every 8 steps (scatter-store drain off critical path)
// ---------------------------------------------------------------------------

typedef __bf16 bf16_t;
typedef __bf16 bf16x8 __attribute__((ext_vector_type(8)));
typedef __bf16 bf16x4v __attribute__((ext_vector_type(4)));
typedef float f32x4 __attribute__((ext_vector_type(4)));

#define MFMA_BF16(a, b, c) __builtin_amdgcn_mfma_f32_16x16x32_bf16((a), (b), (c), 0, 0, 0)

__device__ __forceinline__ float sigm_(float x) { return 1.f / (1.f + __expf(-x)); }
__device__ __forceinline__ float tanh_(float x) {
  x = fminf(20.f, fmaxf(-20.f, x));
  float e = __expf(-2.f * x);
  return (1.f - e) / (1.f + e);
}

__device__ __forceinline__ unsigned long long aload8(const unsigned long long* p) {
  return __hip_atomic_load(p, __ATOMIC_RELAXED, __HIP_MEMORY_SCOPE_AGENT);
}
__device__ __forceinline__ void astore8(unsigned long long* p, unsigned long long v) {
  __hip_atomic_store(p, v, __ATOMIC_RELAXED, __HIP_MEMORY_SCOPE_AGENT);
}

// Poll NG flag lines (stride 32 uints) until all >= tgt. RELAXED loads only.
// Called by wave 0 only; whole block released via the following barrier.
template <int NG>
__device__ __forceinline__ void wait_flags(const unsigned* base, unsigned tgt) {
  const int lane = threadIdx.x & 63;
  for (;;) {
    unsigned f = tgt;
    if (lane < NG)
      f = __hip_atomic_load(base + lane * 32, __ATOMIC_RELAXED, __HIP_MEMORY_SCOPE_AGENT);
    if (__all((int)(f >= tgt))) break;
    __builtin_amdgcn_s_sleep(2);
  }
  __asm__ __volatile__("" ::: "memory");   // no compiler reordering across the spin
}

union U16 { struct { unsigned long long a, b; } s; bf16x8 v; };
union U8  { bf16x4v v; unsigned long long u; };

__global__ void init_bar(unsigned* flags) {
  int i = blockIdx.x * 256 + threadIdx.x;
  flags[i] = 0u;   // grid sized to cover exactly the flag region
}

// ---------------------------- fp32 -> bf16 convert -------------------------
__global__ void cvt4(const float* __restrict__ in, bf16_t* __restrict__ out, int n4) {
  int i = blockIdx.x * blockDim.x + threadIdx.x;
  int stride = gridDim.x * blockDim.x;
  for (; i < n4; i += stride) {
    float4 v = ((const float4*)in)[i];
    bf16x4v o;
    o.x = (bf16_t)v.x; o.y = (bf16_t)v.y; o.z = (bf16_t)v.z; o.w = (bf16_t)v.w;
    ((bf16x4v*)out)[i] = o;
  }
}

// ------------------------------- bf16 GEMM ---------------------------------
__global__ void __launch_bounds__(256, 2)
gemm_bt(const bf16_t* __restrict__ A, const bf16_t* __restrict__ B,
        bf16_t* __restrict__ C, int M, int N, int K) {
  const int tid = threadIdx.x;
  const int w = tid >> 6, lane = tid & 63, quad = lane >> 4, l15 = lane & 15;
  const int ntiles = N >> 7;
  const int m0 = (blockIdx.x / ntiles) << 7;
  const int n0 = (blockIdx.x % ntiles) << 7;
  const int wm = (w >> 1) << 6, wn = (w & 1) << 6;

  __shared__ bf16_t As[128 * 72];
  __shared__ bf16_t Bs[128 * 72];

  const f32x4 z4 = {0.f, 0.f, 0.f, 0.f};
  f32x4 acc[4][4];
#pragma unroll
  for (int i = 0; i < 4; ++i)
#pragma unroll
    for (int j = 0; j < 4; ++j) acc[i][j] = z4;

  const int nk = K >> 6;
  for (int kt = 0; kt < nk; ++kt) {
    uint4 av[4], bv[4];
#pragma unroll
    for (int i = 0; i < 4; ++i) {
      int cid = tid + i * 256;
      int r = cid >> 3, c = cid & 7;
      av[i] = *(const uint4*)&A[(size_t)(m0 + r) * K + kt * 64 + c * 8];
      bv[i] = *(const uint4*)&B[(size_t)(n0 + r) * K + kt * 64 + c * 8];
    }
    __syncthreads();
#pragma unroll
    for (int i = 0; i < 4; ++i) {
      int cid = tid + i * 256;
      int r = cid >> 3, c = cid & 7;
      *(uint4*)&As[r * 72 + c * 8] = av[i];
      *(uint4*)&Bs[r * 72 + c * 8] = bv[i];
    }
    __syncthreads();
#pragma unroll
    for (int s = 0; s < 2; ++s) {
      bf16x8 af[4], bfr[4];
#pragma unroll
      for (int i = 0; i < 4; ++i)
        af[i] = *(const bf16x8*)&As[(wm + i * 16 + l15) * 72 + s * 32 + quad * 8];
#pragma unroll
      for (int j = 0; j < 4; ++j)
        bfr[j] = *(const bf16x8*)&Bs[(wn + j * 16 + l15) * 72 + s * 32 + quad * 8];
#pragma unroll
      for (int i = 0; i < 4; ++i)
#pragma unroll
        for (int j = 0; j < 4; ++j)
          acc[i][j] = MFMA_BF16(af[i], bfr[j], acc[i][j]);
    }
  }
#pragma unroll
  for (int i = 0; i < 4; ++i)
#pragma unroll
    for (int j = 0; j < 4; ++j)
#pragma unroll
      for (int p = 0; p < 4; ++p) {
        int row = m0 + wm + i * 16 + quad * 4 + p;
        int col = n0 + wn + j * 16 + l15;
        C[(size_t)row * N + col] = (bf16_t)acc[i][j][p];
      }
}

// ----------------------- fwd/rev LSTM recurrence ---------------------------
// 128 blocks = dir(2) x bg(16: 16 rows) x hsp(4: 64 hid). Sync group = 4.
// Flag[group][hsp] = last published step (single writer, atomic store).
// hb layout: [par(2)][dir(2)][256 rows][256 hid] bf16.
// h_cat staged in 16KB LDS ring, dumped coalesced every 8 steps.
__global__ void __launch_bounds__(256, 1)
lstm_fr(const bf16_t* __restrict__ gx, const bf16_t* __restrict__ whh,
        const float* __restrict__ b_f, const float* __restrict__ b_r,
        bf16_t* __restrict__ h_cat, bf16_t* __restrict__ hb,
        unsigned* __restrict__ flags) {
  const int tid = threadIdx.x;
  const int w = tid >> 6, lane = tid & 63, quad = lane >> 4, l15 = lane & 15;
  const int dir = blockIdx.x >> 6;
  const int bg = (blockIdx.x >> 2) & 15;
  const int hsp = blockIdx.x & 3;
  const int rows0 = bg << 4;
  const int hid0 = hsp << 6;
  unsigned* fgrp = flags + (dir * 16 + bg) * 128;   // 4 lines x 32 uints
  unsigned* fmine = fgrp + hsp * 32;

  __shared__ bf16_t Ws[256 * 264];   // packed row = g*64+hh, K=256 (+8 pad)
  __shared__ bf16_t hcb[8 * 16 * 64]; // h_cat ring: [tloc][brow][hid]  16KB
  const bf16_t* Wg = whh + (size_t)dir * 262144;
#pragma unroll
  for (int i = 0; i < 32; ++i) {
    int id = tid + i * 256;          // 8192 = 256 rows x 32 chunks(16B)
    int r = id >> 5, c = id & 31;
    int g = r >> 6, hh = r & 63;
    *(uint4*)&Ws[r * 264 + c * 8] =
        *(const uint4*)&Wg[(size_t)(g * 256 + hid0 + hh) * 256 + c * 8];
  }
  const float* bias = dir ? b_r : b_f;
  const int hid = hid0 + w * 16 + quad * 4;   // 4 consecutive hid per lane
  float br[4][4];
#pragma unroll
  for (int g = 0; g < 4; ++g)
#pragma unroll
    for (int p = 0; p < 4; ++p) br[g][p] = bias[g * 256 + hid + p];
  const int brow = rows0 + l15;
  float c4[4] = {0.f, 0.f, 0.f, 0.f};
  const f32x4 z4 = {0.f, 0.f, 0.f, 0.f};
  __syncthreads();

  for (int t = 1; t <= 128; ++t) {
    const int tt = dir ? (128 - t) : (t - 1);
    // gate prefetch: independent of flags, overlaps the poll
    const size_t gbase = ((size_t)brow * 128 + tt) * 2048 + (size_t)dir * 1024;
    bf16x4v gp[4];
#pragma unroll
    for (int g = 0; g < 4; ++g) gp[g] = *(const bf16x4v*)&gx[gbase + g * 256 + hid];

    f32x4 acc[4];
#pragma unroll
    for (int g = 0; g < 4; ++g) acc[g] = z4;

    if (t >= 2) {
      if (w == 0) wait_flags<4>(fgrp, (unsigned)(t - 1));
      __syncthreads();                 // broadcast wave-0's poll result
      const unsigned long long* hrow = (const unsigned long long*)
          (hb + (((size_t)((t & 1) ^ 1) * 2 + dir) * 256 + brow) * 256);
#pragma unroll
      for (int ks = 0; ks < 8; ++ks) {
        U16 u;
        u.s.a = aload8(hrow + ks * 8 + quad * 2);
        u.s.b = aload8(hrow + ks * 8 + quad * 2 + 1);
#pragma unroll
        for (int g = 0; g < 4; ++g) {
          bf16x8 af = *(const bf16x8*)&Ws[(g * 64 + w * 16 + l15) * 264 + ks * 32 + quad * 8];
          acc[g] = MFMA_BF16(af, u.v, acc[g]);
        }
      }
    }
    // epilogue: lane holds all 4 gates for (batch=brow, hid..hid+3)
    bf16x4v hv;
#pragma unroll
    for (int p = 0; p < 4; ++p) {
      float Pi = acc[0][p] + (float)gp[0][p] + br[0][p];
      float Pf = acc[1][p] + (float)gp[1][p] + br[1][p];
      float Pg = acc[2][p] + (float)gp[2][p] + br[2][p];
      float Po = acc[3][p] + (float)gp[3][p] + br[3][p];
      float cc = sigm_(Pf) * c4[p] + sigm_(Pi) * tanh_(Pg);
      c4[p] = cc;
      hv[p] = (bf16_t)(sigm_(Po) * tanh_(cc));
    }
    // stage h into the LDS ring (dumped coalesced every 8 steps)
    *(bf16x4v*)&hcb[(((t - 1) & 7) * 16 + l15) * 64 + w * 16 + quad * 4] = hv;

    if (t < 128) {
      U8 cv; cv.v = hv;
      astore8((unsigned long long*)(hb + (((size_t)(t & 1) * 2 + dir) * 256 + brow) * 256 + hid),
              cv.u);
      __syncthreads();   // vmcnt(0) drain of ALL waves' h stores (+ LDS ring)
      if (tid == 0)
        __hip_atomic_store(fmine, (unsigned)t, __ATOMIC_RELEASE, __HIP_MEMORY_SCOPE_AGENT);
    } else {
      __syncthreads();   // ring writes visible for the final dump
    }

    if ((t & 7) == 0) {
      // dump 8 steps: 128 rows x 128B, full-line coalesced writes
      const int r = tid >> 1, half = tid & 1;
      const int tloc = r >> 4, bl = r & 15;
      const int tp = t - 8 + tloc;                  // t' - 1
      const int ttd = dir ? (127 - tp) : tp;
      const uint4* src = (const uint4*)&hcb[(tloc * 16 + bl) * 64 + half * 32];
      uint4* dst = (uint4*)&h_cat[((size_t)(rows0 + bl) * 128 + ttd) * 512 +
                                  dir * 256 + hid0 + half * 32];
#pragma unroll
      for (int q = 0; q < 4; ++q) dst[q] = src[q];
    }
  }
}

// ------------------------ sentence LSTM recurrence -------------------------
// 128 blocks = bg(8: 32 rows) x hsp(16: 32 hid). Sync group = 16.
// hb layout: [par(2)][256 rows][512 hid] bf16.
__global__ void __launch_bounds__(256, 1)
lstm_s(const bf16_t* __restrict__ gs, const bf16_t* __restrict__ wsh,
       const float* __restrict__ b_s, float* __restrict__ hT,
       bf16_t* __restrict__ hb, unsigned* __restrict__ flags) {
  const int tid = threadIdx.x;
  const int w = tid >> 6, lane = tid & 63, quad = lane >> 4, l15 = lane & 15;
  const int bg = blockIdx.x >> 4;
  const int hsp = blockIdx.x & 15;
  const int rows0 = bg << 5;
  const int hid0 = hsp << 5;
  const int nt = w & 1, hb2 = w >> 1;         // wave: batch-half, hid-half
  unsigned* fgrp = flags + bg * 512;          // 16 lines x 32 uints
  unsigned* fmine = fgrp + hsp * 32;

  __shared__ bf16_t Ws[128 * 520];   // packed row = g*32+hh, K=512 (+8 pad)
#pragma unroll
  for (int i = 0; i < 32; ++i) {
    int id = tid + i * 256;          // 8192 = 128 rows x 64 chunks(16B)
    int r = id >> 6, c = id & 63;
    int g = r >> 5, hh = r & 31;
    *(uint4*)&Ws[r * 520 + c * 8] =
        *(const uint4*)&wsh[(size_t)(g * 512 + hid0 + hh) * 512 + c * 8];
  }
  const int hid = hid0 + hb2 * 16 + quad * 4;
  float br[4][4];
#pragma unroll
  for (int g = 0; g < 4; ++g)
#pragma unroll
    for (int p = 0; p < 4; ++p) br[g][p] = b_s[g * 512 + hid + p];
  const int brow = rows0 + nt * 16 + l15;
  float c4[4] = {0.f, 0.f, 0.f, 0.f};
  const f32x4 z4 = {0.f, 0.f, 0.f, 0.f};
  __syncthreads();

  for (int t = 1; t <= 128; ++t) {
    const size_t gbase = ((size_t)brow * 128 + (t - 1)) * 2048;
    bf16x4v gp[4];
#pragma unroll
    for (int g = 0; g < 4; ++g) gp[g] = *(const bf16x4v*)&gs[gbase + g * 512 + hid];

    f32x4 acc[4];
#pragma unroll
    for (int g = 0; g < 4; ++g) acc[g] = z4;

    if (t >= 2) {
      if (w == 0) wait_flags<16>(fgrp, (unsigned)(t - 1));
      __syncthreads();                 // broadcast wave-0's poll result
      const unsigned long long* hrow = (const unsigned long long*)
          (hb + ((size_t)((t & 1) ^ 1) * 256 + brow) * 512);
#pragma unroll
      for (int ks = 0; ks < 16; ++ks) {
        U16 u;
        u.s.a = aload8(hrow + ks * 8 + quad * 2);
        u.s.b = aload8(hrow + ks * 8 + quad * 2 + 1);
#pragma unroll
        for (int g = 0; g < 4; ++g) {
          bf16x8 af = *(const bf16x8*)&Ws[(g * 32 + hb2 * 16 + l15) * 520 + ks * 32 + quad * 8];
          acc[g] = MFMA_BF16(af, u.v, acc[g]);
        }
      }
    }
    bf16x4v hv;
    float hf[4];
#pragma unroll
    for (int p = 0; p < 4; ++p) {
      float Pi = acc[0][p] + (float)gp[0][p] + br[0][p];
      float Pf = acc[1][p] + (float)gp[1][p] + br[1][p];
      float Pg = acc[2][p] + (float)gp[2][p] + br[2][p];
      float Po = acc[3][p] + (float)gp[3][p] + br[3][p];
      float cc = sigm_(Pf) * c4[p] + sigm_(Pi) * tanh_(Pg);
      c4[p] = cc;
      hf[p] = sigm_(Po) * tanh_(cc);
      hv[p] = (bf16_t)hf[p];
    }
    if (t < 128) {
      U8 cv; cv.v = hv;
      astore8((unsigned long long*)(hb + ((size_t)(t & 1) * 256 + brow) * 512 + hid), cv.u);
      __syncthreads();
      if (tid == 0)
        __hip_atomic_store(fmine, (unsigned)t, __ATOMIC_RELEASE, __HIP_MEMORY_SCOPE_AGENT);
    } else {
      *(float4*)&hT[(size_t)brow * 512 + hid] = make_float4(hf[0], hf[1], hf[2], hf[3]);
    }
  }
}

// ------------------------------- emissions ---------------------------------
__global__ void emis_k(const float* __restrict__ hT, const float* __restrict__ lin_w,
                       const float* __restrict__ lin_b, float* __restrict__ em) {
  const int idx = blockIdx.x * 256 + threadIdx.x;
  const int s = idx >> 4, c = idx & 15;
  const float4* h4 = (const float4*)(hT + (size_t)s * 512);
  const float4* w4 = (const float4*)(lin_w + (size_t)c * 512);
  float acc = lin_b[c];
  for (int k = 0; k < 128; ++k) {
    float4 a = h4[k], b = w4[k];
    acc += a.x * b.x + a.y * b.y + a.z * b.z + a.w * b.w;
  }
  em[idx] = acc;
}

// ---------------------------------- CRF ------------------------------------
__global__ void crf_k(const float* __restrict__ em, const int* __restrict__ y,
                      const float* __restrict__ cs, const float* __restrict__ ce,
                      const float* __restrict__ tr, float* __restrict__ out) {
  __shared__ float alpha[16];
  __shared__ float trs[256];
  const int lane = threadIdx.x;
  const int i = lane & 15, jg = lane >> 4;

  for (int k = lane; k < 256; k += 64) trs[k] = tr[k];
  __syncthreads();

  float np = 0.f;
  for (int s = lane; s < 256; s += 64) np += em[s * 16 + y[s]];
  for (int s = lane + 1; s < 256; s += 64) np += trs[y[s - 1] * 16 + y[s]];
#pragma unroll
  for (int off = 32; off > 0; off >>= 1) np += __shfl_down(np, off, 64);

  if (lane < 16) alpha[lane] = cs[lane] + em[lane];
  __syncthreads();

  for (int s = 1; s < 256; ++s) {
    const float* e = em + s * 16;
    float v[4];
#pragma unroll
    for (int jj = 0; jj < 4; ++jj) v[jj] = alpha[i] + trs[i * 16 + (jj * 4 + jg)];
    float res[4];
#pragma unroll
    for (int jj = 0; jj < 4; ++jj) {
      float m = v[jj];
      m = fmaxf(m, __shfl_xor(m, 1, 64));
      m = fmaxf(m, __shfl_xor(m, 2, 64));
      m = fmaxf(m, __shfl_xor(m, 4, 64));
      m = fmaxf(m, __shfl_xor(m, 8, 64));
      float ex = __expf(v[jj] - m);
      ex += __shfl_xor(ex, 1, 64);
      ex += __shfl_xor(ex, 2, 64);
      ex += __shfl_xor(ex, 4, 64);
      ex += __shfl_xor(ex, 8, 64);
      res[jj] = m + __logf(ex) + e[jj * 4 + jg];
    }
#pragma unroll
    for (int jj = 0; jj < 4; ++jj)
      if (i == 0) alpha[jj * 4 + jg] = res[jj];
  }

  float v = (lane < 16) ? (alpha[lane] + ce[lane]) : -3.0e38f;
  float m = v;
#pragma unroll
  for (int off = 32; off > 0; off >>= 1) m = fmaxf(m, __shfl_xor(m, off, 64));
  float ex = __expf(v - m);
#pragma unroll
  for (int off = 32; off > 0; off >>= 1) ex += __shfl_xor(ex, off, 64);
  float denom = m + __logf(ex);

  if (lane == 0) {
    float num = np + cs[y[0]] + ce[y[255]];
    out[0] = num - denom;
  }
}

// ------------------------------ orchestration ------------------------------
extern "C" void kernel_launch(void* const* d_in, const int* in_sizes, int n_in,
                              void* d_out, int out_size, void* d_ws, size_t ws_size,
                              hipStream_t stream) {
  const float* x = (const float*)d_in[0];
  const int* y = (const int*)d_in[1];
  const float* w_ih_f = (const float*)d_in[3];
  const float* w_hh_f = (const float*)d_in[4];
  const float* b_f = (const float*)d_in[5];
  const float* w_ih_r = (const float*)d_in[6];
  const float* w_hh_r = (const float*)d_in[7];
  const float* b_r = (const float*)d_in[8];
  const float* w_ih_s = (const float*)d_in[9];
  const float* w_hh_s = (const float*)d_in[10];
  const float* b_s = (const float*)d_in[11];
  const float* lin_w = (const float*)d_in[12];
  const float* lin_b = (const float*)d_in[13];
  const float* crf_s = (const float*)d_in[14];
  const float* crf_e = (const float*)d_in[15];
  const float* crf_t = (const float*)d_in[16];

  char* ws = (char*)d_ws;
  size_t off = 0;
  auto take = [&](size_t bytes) {
    void* p = ws + off;
    off += (bytes + 255) & ~(size_t)255;
    return p;
  };
  bf16_t* Wx  = (bf16_t*)take((size_t)2048 * 768 * 2);
  bf16_t* Whh = (bf16_t*)take((size_t)2 * 1024 * 256 * 2);
  bf16_t* Wsi = (bf16_t*)take((size_t)2048 * 512 * 2);
  bf16_t* Wsh = (bf16_t*)take((size_t)2048 * 512 * 2);
  bf16_t* gx  = (bf16_t*)take((size_t)32768 * 2048 * 2);
  bf16_t* xb  = (bf16_t*)take((size_t)32768 * 768 * 2);   // 48MB region
  float* hT   = (float*)take((size_t)256 * 512 * 4);
  float* em   = (float*)take((size_t)4096 * 4);
  bf16_t* gs = gx;       // gx dead after lstm_fr
  bf16_t* hcat = xb;     // xb dead after gemm1
  // dead tail of xb region after gemm1 consumes it
  char* tail = (char*)xb + 33554432;
  bf16_t* hb_fr = (bf16_t*)tail;                 // 2*2*256*256*2 = 512KB
  bf16_t* hb_s  = (bf16_t*)(tail + 524288);      // 2*256*512*2   = 512KB
  unsigned* flags_fr = (unsigned*)(tail + 1048576);          // 32 grp x 128 uints
  unsigned* flags_s  = (unsigned*)(tail + 1048576 + 16384);  // 8 grp x 512 uints
  (void)ws_size; (void)in_sizes; (void)n_in; (void)out_size;

  // phase 1: converts
  cvt4<<<2048, 256, 0, stream>>>(x, xb, 32768 * 768 / 4);
  cvt4<<<64, 256, 0, stream>>>(w_ih_f, Wx, 786432 / 4);
  cvt4<<<64, 256, 0, stream>>>(w_ih_r, Wx + 786432, 786432 / 4);
  cvt4<<<32, 256, 0, stream>>>(w_hh_f, Whh, 262144 / 4);
  cvt4<<<32, 256, 0, stream>>>(w_hh_r, Whh + 262144, 262144 / 4);
  cvt4<<<64, 256, 0, stream>>>(w_ih_s, Wsi, 1048576 / 4);
  cvt4<<<64, 256, 0, stream>>>(w_hh_s, Wsh, 1048576 / 4);

  // phase 2: input gates for fwd+rev   (M=32768, N=2048, K=768)
  gemm_bt<<<4096, 256, 0, stream>>>(xb, Wx, gx, 32768, 2048, 768);

  // flags live in xb tail — init only after gemm1 is done with xb
  // (zero both arrays: 4096 + 4096 uints = 32 blocks x 256)
  init_bar<<<32, 256, 0, stream>>>(flags_fr);

  // phase 3: fwd/rev recurrences -> h_cat
  lstm_fr<<<128, 256, 0, stream>>>(gx, Whh, b_f, b_r, hcat, hb_fr, flags_fr);

  // phase 4: sentence input gates     (M=32768, N=2048, K=512)
  gemm_bt<<<4096, 256, 0, stream>>>(hcat, Wsi, gs, 32768, 2048, 512);

  // phase 5: sentence recurrence -> hT
  lstm_s<<<128, 256, 0, stream>>>(gs, Wsh, b_s, hT, hb_s, flags_s);

  // phase 6: emissions + CRF
  emis_k<<<16, 256, 0, stream>>>(hT, lin_w, lin_b, em);
  crf_k<<<1, 64, 0, stream>>>(em, y, crf_s, crf_e, crf_t, (float*)d_out);
}